// Round 1
// baseline (281.312 us; speedup 1.0000x reference)
//
#include <hip/hip_runtime.h>
#include <hip/hip_bf16.h>

#define SEQ 2048
#define EMB 2048
#define NH 16
#define WIN 256
#define HD 128
#define KDIM 2048
#define NDIM 2048

typedef __bf16 bf16x8 __attribute__((ext_vector_type(8)));
typedef float f32x4 __attribute__((ext_vector_type(4)));

__device__ __forceinline__ ushort f2bf(float f) {
  // RNE float->bf16 (finite values only here)
  unsigned int x = __float_as_uint(f);
  unsigned int r = (x + 0x7fffu + ((x >> 16) & 1u)) >> 16;
  return (ushort)r;
}

// ---------------- W transpose: f32 [K][N] -> blocked swizzled bf16 tiles ----
// tile (nblk,kblk): 128 n-rows x 32 k, stored contiguous 4096 elems.
// within tile: row r (=n local), chunk c_store holds logical k-chunk c_store ^ ((r>>1)&3)
__global__ __launch_bounds__(256) void wtrans_kernel(
    const float* __restrict__ w0, const float* __restrict__ w1,
    const float* __restrict__ w2, const float* __restrict__ w3,
    ushort* __restrict__ wt) {
  __shared__ __align__(16) float tf[32 * 132];
  const int t = threadIdx.x;
  const int nblk = blockIdx.x, kblk = blockIdx.y, mat = blockIdx.z;
  const float* Wp = mat == 0 ? w0 : mat == 1 ? w1 : mat == 2 ? w2 : w3;
  const int n0 = nblk * 128, k0 = kblk * 32;
#pragma unroll
  for (int p = 0; p < 4; ++p) {
    int kk = (t >> 5) + 8 * p;
    int nn = (t & 31) * 4;
    float4 v = *(const float4*)&Wp[(size_t)(k0 + kk) * NDIM + n0 + nn];
    *(float4*)&tf[kk * 132 + nn] = v;
  }
  __syncthreads();
  ushort* dst = wt + (size_t)mat * ((size_t)NDIM * KDIM) +
                (size_t)(nblk * 64 + kblk) * 4096;
#pragma unroll
  for (int p = 0; p < 2; ++p) {
    int idx = p * 256 + t;
    int r = idx >> 2, cs = idx & 3;
    int c = cs ^ ((r >> 1) & 3);
    union { ushort u[8]; uint4 v; } pk;
#pragma unroll
    for (int j = 0; j < 8; ++j) pk.u[j] = f2bf(tf[(c * 8 + j) * 132 + r]);
    *(uint4*)&dst[idx * 8] = pk.v;  // r*32 + cs*8 == idx*8 -> fully coalesced
  }
}

// ---------------- GEMM: C[M][N] = A[M][K] @ W[K][N] + bias -----------------
// MODE 1: QKV fused (z picks matrix; A is f32 x; writes k/v f32 to d_out
//         in (B,H,S,D) layout and Q bf16 to ws).
// MODE 0: out proj (A is bf16 ctx; plain f32 row-major out).
template <int MODE>
__global__ __launch_bounds__(256) void gemm_kernel(
    const void* __restrict__ Aptr, const ushort* __restrict__ Wt,
    const float* __restrict__ b0, const float* __restrict__ b1,
    const float* __restrict__ b2, float* __restrict__ outF,
    ushort* __restrict__ outQ) {
  __shared__ __align__(16) ushort As[128 * 32];
  __shared__ __align__(16) ushort Bs[128 * 32];
  const int t = threadIdx.x;
  const int mblk = blockIdx.x, nblk = blockIdx.y, z = blockIdx.z;
  const int m0 = mblk * 128, n0 = nblk * 128;
  const ushort* wtile = Wt + (size_t)z * ((size_t)NDIM * KDIM) +
                        (size_t)(nblk * 64) * 4096;
  const int lane = t & 63, wid = t >> 6;
  const int l15 = lane & 15, lg = lane >> 4;
  const int wm = wid >> 1, wn = wid & 1;
  f32x4 acc[4][4] = {};

  for (int kt = 0; kt < KDIM / 32; ++kt) {
    __syncthreads();
    {  // B stage: blocked source is already LDS-ordered -> linear copy
      const uint4* src = (const uint4*)(wtile + (size_t)kt * 4096);
#pragma unroll
      for (int p = 0; p < 2; ++p) {
        int idx = p * 256 + t;
        *(uint4*)&Bs[idx * 8] = src[idx];
      }
    }
#pragma unroll
    for (int p = 0; p < 2; ++p) {  // A stage (swizzled write)
      int r = (t >> 2) + 64 * p;
      int cs = t & 3;
      int c = cs ^ ((r >> 1) & 3);
      union { ushort u[8]; uint4 v; } pk;
      if (MODE == 1) {
        const float* ap = (const float*)Aptr + (size_t)(m0 + r) * KDIM + kt * 32 + c * 8;
        float4 f0 = *(const float4*)ap;
        float4 f1 = *(const float4*)(ap + 4);
        pk.u[0] = f2bf(f0.x); pk.u[1] = f2bf(f0.y);
        pk.u[2] = f2bf(f0.z); pk.u[3] = f2bf(f0.w);
        pk.u[4] = f2bf(f1.x); pk.u[5] = f2bf(f1.y);
        pk.u[6] = f2bf(f1.z); pk.u[7] = f2bf(f1.w);
      } else {
        pk.v = *(const uint4*)((const ushort*)Aptr + (size_t)(m0 + r) * KDIM + kt * 32 + c * 8);
      }
      *(uint4*)&As[r * 32 + cs * 8] = pk.v;
    }
    __syncthreads();
    bf16x8 af[4], bfr[4];
#pragma unroll
    for (int mf = 0; mf < 4; ++mf) {
      int r = wm * 64 + mf * 16 + l15;
      af[mf] = *(const bf16x8*)&As[r * 32 + ((lg ^ ((r >> 1) & 3)) * 8)];
    }
#pragma unroll
    for (int nf = 0; nf < 4; ++nf) {
      int r = wn * 64 + nf * 16 + l15;
      bfr[nf] = *(const bf16x8*)&Bs[r * 32 + ((lg ^ ((r >> 1) & 3)) * 8)];
    }
#pragma unroll
    for (int mf = 0; mf < 4; ++mf)
#pragma unroll
      for (int nf = 0; nf < 4; ++nf)
        acc[mf][nf] = __builtin_amdgcn_mfma_f32_16x16x32_bf16(
            af[mf], bfr[nf], acc[mf][nf], 0, 0, 0);
  }

  const float* bias = (MODE == 0) ? b0 : (z == 0 ? b0 : z == 1 ? b1 : b2);
#pragma unroll
  for (int nf = 0; nf < 4; ++nf) {
    int nl = wn * 64 + nf * 16 + l15;
    int n = n0 + nl;
    float bv = bias[n];
#pragma unroll
    for (int mf = 0; mf < 4; ++mf) {
#pragma unroll
      for (int r = 0; r < 4; ++r) {
        int m = m0 + wm * 64 + mf * 16 + lg * 4 + r;
        float val = acc[mf][nf][r] + bv;
        if (MODE == 0) {
          outF[(size_t)m * NDIM + n] = val;
        } else {
          int b = m >> 11, s = m & 2047;
          // n-tile (128) == head dim -> h = nblk, d = nl
          size_t idx = (((size_t)b * NH + nblk) * SEQ + s) * HD + nl;
          if (z == 0) outQ[idx] = f2bf(val);
          else outF[(z == 1 ? 8388608u : 16777216u) + idx] = val;
        }
      }
    }
  }
}

// ---------------- sliding-window flash attention ---------------------------
// block: (bh, qblk of 64). 4 waves x 16 q-rows. K-tiles of 64 keys.
__global__ __launch_bounds__(256) void attn_kernel(
    const ushort* __restrict__ Qb, const float* __restrict__ Kf,
    const float* __restrict__ Vf, ushort* __restrict__ ctx) {
  __shared__ __align__(16) ushort Kl[64 * 128];   // [key][d], chunk^=(key&7)
  __shared__ __align__(16) ushort Vl[128 * 72];   // [d][key], pad stride 72
  __shared__ __align__(16) ushort Pl[4 * 16 * 72];
  const int t = threadIdx.x;
  const int bh = blockIdx.x;
  const int q0 = blockIdx.y * 64;
  const int lane = t & 63, w = t >> 6;
  const int l15 = lane & 15, lg = lane >> 4;
  const int b = bh >> 4, h = bh & 15;
  const ushort* Qbase = Qb + (size_t)bh * SEQ * HD;
  const float* Kbase = Kf + (size_t)bh * SEQ * HD;
  const float* Vbase = Vf + (size_t)bh * SEQ * HD;

  bf16x8 aq[4];
#pragma unroll
  for (int ds = 0; ds < 4; ++ds)
    aq[ds] = *(const bf16x8*)&Qbase[(size_t)(q0 + w * 16 + l15) * HD + ds * 32 + lg * 8];

  f32x4 accc[8] = {};
  float mrow[4], lrow[4];
#pragma unroll
  for (int r = 0; r < 4; ++r) { mrow[r] = -1e30f; lrow[r] = 0.f; }

  int ktlo = (q0 - WIN + 1) >> 6;
  if (ktlo < 0) ktlo = 0;
  const int kthi = q0 >> 6;

  for (int kt = ktlo; kt <= kthi; ++kt) {
    __syncthreads();
#pragma unroll
    for (int p = 0; p < 4; ++p) {  // K stage, f32->bf16, XOR swizzle
      int idx = p * 256 + t;
      int row = idx >> 4, cs = idx & 15;
      int c = cs ^ (row & 7);
      const float* sp = &Kbase[(size_t)(kt * 64 + row) * HD + c * 8];
      float4 f0 = *(const float4*)sp;
      float4 f1 = *(const float4*)(sp + 4);
      union { ushort u[8]; uint4 v; } pk;
      pk.u[0] = f2bf(f0.x); pk.u[1] = f2bf(f0.y);
      pk.u[2] = f2bf(f0.z); pk.u[3] = f2bf(f0.w);
      pk.u[4] = f2bf(f1.x); pk.u[5] = f2bf(f1.y);
      pk.u[6] = f2bf(f1.z); pk.u[7] = f2bf(f1.w);
      *(uint4*)&Kl[row * 128 + cs * 8] = pk.v;
    }
#pragma unroll
    for (int p = 0; p < 4; ++p) {  // V stage transposed [d][key]
      int idx = p * 256 + t;
      int key = idx & 63, dc = idx >> 6;
      const float* sp = &Vbase[(size_t)(kt * 64 + key) * HD + dc * 8];
      float4 f0 = *(const float4*)sp;
      float4 f1 = *(const float4*)(sp + 4);
      Vl[(dc * 8 + 0) * 72 + key] = f2bf(f0.x);
      Vl[(dc * 8 + 1) * 72 + key] = f2bf(f0.y);
      Vl[(dc * 8 + 2) * 72 + key] = f2bf(f0.z);
      Vl[(dc * 8 + 3) * 72 + key] = f2bf(f0.w);
      Vl[(dc * 8 + 4) * 72 + key] = f2bf(f1.x);
      Vl[(dc * 8 + 5) * 72 + key] = f2bf(f1.y);
      Vl[(dc * 8 + 6) * 72 + key] = f2bf(f1.z);
      Vl[(dc * 8 + 7) * 72 + key] = f2bf(f1.w);
    }
    __syncthreads();

    f32x4 sacc[4] = {};
#pragma unroll
    for (int ds = 0; ds < 4; ++ds) {
#pragma unroll
      for (int kf = 0; kf < 4; ++kf) {
        int key = kf * 16 + l15;
        bf16x8 kb = *(const bf16x8*)&Kl[key * 128 + (((ds * 4 + lg) ^ (key & 7)) * 8)];
        sacc[kf] = __builtin_amdgcn_mfma_f32_16x16x32_bf16(aq[ds], kb, sacc[kf], 0, 0, 0);
      }
    }

    const float scale = 0.08838834764831845f;  // 1/sqrt(128)
    const float L2E = 1.4426950408889634f;
#pragma unroll
    for (int r = 0; r < 4; ++r) {
      int q = q0 + w * 16 + lg * 4 + r;
      float sv[4];
      float mx = -1e30f;
#pragma unroll
      for (int kf = 0; kf < 4; ++kf) {
        int key = kt * 64 + kf * 16 + l15;
        float s = sacc[kf][r] * scale;
        bool valid = (key <= q) && (key + WIN > q);
        s = valid ? s : -1e30f;
        sv[kf] = s;
        mx = fmaxf(mx, s);
      }
      mx = fmaxf(mx, __shfl_xor(mx, 1));
      mx = fmaxf(mx, __shfl_xor(mx, 2));
      mx = fmaxf(mx, __shfl_xor(mx, 4));
      mx = fmaxf(mx, __shfl_xor(mx, 8));
      float mnew = fmaxf(mrow[r], mx);
      float sf = exp2f((mrow[r] - mnew) * L2E);
      float ps = 0.f;
#pragma unroll
      for (int kf = 0; kf < 4; ++kf) {
        float p = (sv[kf] > -1e29f) ? exp2f((sv[kf] - mnew) * L2E) : 0.f;
        ps += p;
        Pl[w * 1152 + (lg * 4 + r) * 72 + kf * 16 + l15] = f2bf(p);
      }
      ps += __shfl_xor(ps, 1);
      ps += __shfl_xor(ps, 2);
      ps += __shfl_xor(ps, 4);
      ps += __shfl_xor(ps, 8);
      lrow[r] = lrow[r] * sf + ps;
      mrow[r] = mnew;
#pragma unroll
      for (int nf = 0; nf < 8; ++nf) accc[nf][r] *= sf;
    }

#pragma unroll
    for (int ks = 0; ks < 2; ++ks) {  // PV
      bf16x8 pa = *(const bf16x8*)&Pl[w * 1152 + l15 * 72 + ks * 32 + lg * 8];
#pragma unroll
      for (int nf = 0; nf < 8; ++nf) {
        bf16x8 vb = *(const bf16x8*)&Vl[(nf * 16 + l15) * 72 + ks * 32 + lg * 8];
        accc[nf] = __builtin_amdgcn_mfma_f32_16x16x32_bf16(pa, vb, accc[nf], 0, 0, 0);
      }
    }
  }

#pragma unroll
  for (int r = 0; r < 4; ++r) {
    int q = q0 + w * 16 + lg * 4 + r;
    float inv = 1.0f / lrow[r];
    size_t rowoff = ((size_t)b * SEQ + q) * EMB + (size_t)h * HD;
#pragma unroll
    for (int nf = 0; nf < 8; ++nf)
      ctx[rowoff + nf * 16 + l15] = f2bf(accc[nf][r] * inv);
  }
}

// ---------------------------------------------------------------------------
extern "C" void kernel_launch(void* const* d_in, const int* in_sizes, int n_in,
                              void* d_out, int out_size, void* d_ws, size_t ws_size,
                              hipStream_t stream) {
  const float* x  = (const float*)d_in[0];
  const float* Wq = (const float*)d_in[1];
  const float* bq = (const float*)d_in[2];
  const float* Wk = (const float*)d_in[3];
  const float* bk = (const float*)d_in[4];
  const float* Wv = (const float*)d_in[5];
  const float* bv = (const float*)d_in[6];
  const float* Wo = (const float*)d_in[7];
  const float* bo = (const float*)d_in[8];
  float* out = (float*)d_out;
  ushort* ws = (ushort*)d_ws;
  // ws layout (ushort elems): Wt 4x4194304 | Qb 8388608 | ctx 8388608 = 64MB
  ushort* Wt  = ws;
  ushort* Qb  = ws + 16777216;
  ushort* ctxb = ws + 25165824;

  wtrans_kernel<<<dim3(16, 64, 4), 256, 0, stream>>>(Wq, Wk, Wv, Wo, Wt);
  gemm_kernel<1><<<dim3(32, 16, 3), 256, 0, stream>>>(x, Wt, bq, bk, bv, out, Qb);
  attn_kernel<<<dim3(32, 32), 256, 0, stream>>>(Qb, out + 8388608, out + 16777216, ctxb);
  gemm_kernel<0><<<dim3(32, 16, 1), 256, 0, stream>>>(ctxb, Wt + (size_t)3 * 4194304,
                                                      bo, nullptr, nullptr, out, nullptr);
}

// Round 2
// 236.572 us; speedup vs baseline: 1.1891x; 1.1891x over previous
//
#include <hip/hip_runtime.h>
#include <hip/hip_bf16.h>

#define SEQ 2048
#define EMB 2048
#define NH 16
#define WIN 256
#define HD 128
#define KDIM 2048
#define NDIM 2048

typedef __bf16 bf16x8 __attribute__((ext_vector_type(8)));
typedef float f32x4 __attribute__((ext_vector_type(4)));

__device__ __forceinline__ ushort f2bf(float f) {
  // RNE float->bf16 (finite values only here)
  unsigned int x = __float_as_uint(f);
  unsigned int r = (x + 0x7fffu + ((x >> 16) & 1u)) >> 16;
  return (ushort)r;
}

__device__ __forceinline__ void gl16(const ushort* g, ushort* l) {
  // async global->LDS, 16B per lane; LDS dest = wave-uniform base + lane*16
  __builtin_amdgcn_global_load_lds(
      (const __attribute__((address_space(1))) ushort*)g,
      (__attribute__((address_space(3))) ushort*)l, 16, 0, 0);
}

// ---------------- x f32 -> bf16 (once; removes 48x per-elem in-loop cvt) ----
__global__ __launch_bounds__(256) void xconv_kernel(
    const float* __restrict__ x, ushort* __restrict__ xb) {
  size_t i = ((size_t)blockIdx.x * 256 + threadIdx.x) * 8;
  float4 f0 = *(const float4*)&x[i];
  float4 f1 = *(const float4*)&x[i + 4];
  union { ushort u[8]; uint4 v; } pk;
  pk.u[0] = f2bf(f0.x); pk.u[1] = f2bf(f0.y);
  pk.u[2] = f2bf(f0.z); pk.u[3] = f2bf(f0.w);
  pk.u[4] = f2bf(f1.x); pk.u[5] = f2bf(f1.y);
  pk.u[6] = f2bf(f1.z); pk.u[7] = f2bf(f1.w);
  *(uint4*)&xb[i] = pk.v;
}

// ---------------- W transpose: f32 [K][N] -> blocked swizzled bf16 tiles ----
// tile (nblk,kblk): 128 n-rows x 32 k, stored contiguous 4096 elems.
// within tile: row r (=n local), chunk c_store holds logical k-chunk c_store ^ ((r>>1)&3)
__global__ __launch_bounds__(256) void wtrans_kernel(
    const float* __restrict__ w0, const float* __restrict__ w1,
    const float* __restrict__ w2, const float* __restrict__ w3,
    ushort* __restrict__ wt) {
  __shared__ __align__(16) float tf[32 * 132];
  const int t = threadIdx.x;
  const int nblk = blockIdx.x, kblk = blockIdx.y, mat = blockIdx.z;
  const float* Wp = mat == 0 ? w0 : mat == 1 ? w1 : mat == 2 ? w2 : w3;
  const int n0 = nblk * 128, k0 = kblk * 32;
#pragma unroll
  for (int p = 0; p < 4; ++p) {
    int kk = (t >> 5) + 8 * p;
    int nn = (t & 31) * 4;
    float4 v = *(const float4*)&Wp[(size_t)(k0 + kk) * NDIM + n0 + nn];
    *(float4*)&tf[kk * 132 + nn] = v;
  }
  __syncthreads();
  ushort* dst = wt + (size_t)mat * ((size_t)NDIM * KDIM) +
                (size_t)(nblk * 64 + kblk) * 4096;
#pragma unroll
  for (int p = 0; p < 2; ++p) {
    int idx = p * 256 + t;
    int r = idx >> 2, cs = idx & 3;
    int c = cs ^ ((r >> 1) & 3);
    union { ushort u[8]; uint4 v; } pk;
#pragma unroll
    for (int j = 0; j < 8; ++j) pk.u[j] = f2bf(tf[(c * 8 + j) * 132 + r]);
    *(uint4*)&dst[idx * 8] = pk.v;  // r*32 + cs*8 == idx*8 -> fully coalesced
  }
}

// ---------------- GEMM: C[M][N] = A[M][K] @ W[K][N] + bias -----------------
// A is bf16 [M][K] row-major (xb or ctx). Staging via global_load_lds w=16:
// LDS dest linear; swizzle baked into per-lane GLOBAL source address.
// MODE 1: QKV fused (z picks matrix; writes k/v f32 to d_out (B,H,S,D),
//         Q bf16 to ws). MODE 0: out proj (plain f32 row-major out).
template <int MODE>
__global__ __launch_bounds__(256) void gemm_kernel(
    const ushort* __restrict__ Ab, const ushort* __restrict__ Wt,
    const float* __restrict__ b0, const float* __restrict__ b1,
    const float* __restrict__ b2, float* __restrict__ outF,
    ushort* __restrict__ outQ) {
  __shared__ __align__(16) ushort As[128 * 32];
  __shared__ __align__(16) ushort Bs[128 * 32];
  const int t = threadIdx.x;
  const int mblk = blockIdx.x, nblk = blockIdx.y, z = blockIdx.z;
  const int m0 = mblk * 128, n0 = nblk * 128;
  const ushort* wtile = Wt + (size_t)z * ((size_t)NDIM * KDIM) +
                        (size_t)(nblk * 64) * 4096;
  const int lane = t & 63, wid = t >> 6;
  const int l15 = lane & 15, lg = lane >> 4;
  const int wm = wid >> 1, wn = wid & 1;
  f32x4 acc[4][4] = {};

  // per-lane staging addresses (slot = wid*128 + j*64 + lane; 16B per slot)
  const int slot0 = wid * 128 + lane;
  const int slot1 = slot0 + 64;
  // A source: row r=slot>>2, stored chunk cs=slot&3 holds global chunk cs^((r>>1)&3)
  const int r0 = slot0 >> 2, c0 = (slot0 & 3) ^ ((r0 >> 1) & 3);
  const int r1 = slot1 >> 2, c1 = (slot1 & 3) ^ ((r1 >> 1) & 3);
  const ushort* aS0 = Ab + (size_t)(m0 + r0) * KDIM + c0 * 8;
  const ushort* aS1 = Ab + (size_t)(m0 + r1) * KDIM + c1 * 8;
  const ushort* bS0 = wtile + slot0 * 8;
  const ushort* bS1 = wtile + slot1 * 8;
  ushort* aD0 = &As[(wid * 128) * 8];
  ushort* aD1 = &As[(wid * 128 + 64) * 8];
  ushort* bD0 = &Bs[(wid * 128) * 8];
  ushort* bD1 = &Bs[(wid * 128 + 64) * 8];

  for (int kt = 0; kt < KDIM / 32; ++kt) {
    __syncthreads();
    gl16(aS0, aD0); gl16(aS1, aD1);
    gl16(bS0, bD0); gl16(bS1, bD1);
    aS0 += 32; aS1 += 32; bS0 += 4096; bS1 += 4096;
    __syncthreads();
    bf16x8 af[4], bfr[4];
#pragma unroll
    for (int mf = 0; mf < 4; ++mf) {
      int r = wm * 64 + mf * 16 + l15;
      af[mf] = *(const bf16x8*)&As[r * 32 + ((lg ^ ((r >> 1) & 3)) * 8)];
    }
#pragma unroll
    for (int nf = 0; nf < 4; ++nf) {
      int r = wn * 64 + nf * 16 + l15;
      bfr[nf] = *(const bf16x8*)&Bs[r * 32 + ((lg ^ ((r >> 1) & 3)) * 8)];
    }
#pragma unroll
    for (int mf = 0; mf < 4; ++mf)
#pragma unroll
      for (int nf = 0; nf < 4; ++nf)
        acc[mf][nf] = __builtin_amdgcn_mfma_f32_16x16x32_bf16(
            af[mf], bfr[nf], acc[mf][nf], 0, 0, 0);
  }

  const float* bias = (MODE == 0) ? b0 : (z == 0 ? b0 : z == 1 ? b1 : b2);
#pragma unroll
  for (int nf = 0; nf < 4; ++nf) {
    int nl = wn * 64 + nf * 16 + l15;
    int n = n0 + nl;
    float bv = bias[n];
#pragma unroll
    for (int mf = 0; mf < 4; ++mf) {
#pragma unroll
      for (int r = 0; r < 4; ++r) {
        int m = m0 + wm * 64 + mf * 16 + lg * 4 + r;
        float val = acc[mf][nf][r] + bv;
        if (MODE == 0) {
          outF[(size_t)m * NDIM + n] = val;
        } else {
          int b = m >> 11, s = m & 2047;
          // n-tile (128) == head dim -> h = nblk, d = nl
          size_t idx = (((size_t)b * NH + nblk) * SEQ + s) * HD + nl;
          if (z == 0) outQ[idx] = f2bf(val);
          else outF[(z == 1 ? 8388608u : 16777216u) + idx] = val;
        }
      }
    }
  }
}

// ---------------- sliding-window flash attention ---------------------------
// block: (bh, qblk of 64). 4 waves x 16 q-rows. K-tiles of 64 keys.
__global__ __launch_bounds__(256) void attn_kernel(
    const ushort* __restrict__ Qb, const float* __restrict__ Kf,
    const float* __restrict__ Vf, ushort* __restrict__ ctx) {
  __shared__ __align__(16) ushort Kl[64 * 128];   // [key][d], chunk^=(key&7)
  __shared__ __align__(16) ushort Vl[128 * 72];   // [d][key], pad stride 72
  __shared__ __align__(16) ushort Pl[4 * 16 * 72];
  const int t = threadIdx.x;
  const int bh = blockIdx.x;
  const int q0 = blockIdx.y * 64;
  const int lane = t & 63, w = t >> 6;
  const int l15 = lane & 15, lg = lane >> 4;
  const int b = bh >> 4, h = bh & 15;
  const ushort* Qbase = Qb + (size_t)bh * SEQ * HD;
  const float* Kbase = Kf + (size_t)bh * SEQ * HD;
  const float* Vbase = Vf + (size_t)bh * SEQ * HD;

  bf16x8 aq[4];
#pragma unroll
  for (int ds = 0; ds < 4; ++ds)
    aq[ds] = *(const bf16x8*)&Qbase[(size_t)(q0 + w * 16 + l15) * HD + ds * 32 + lg * 8];

  f32x4 accc[8] = {};
  float mrow[4], lrow[4];
#pragma unroll
  for (int r = 0; r < 4; ++r) { mrow[r] = -1e30f; lrow[r] = 0.f; }

  int ktlo = (q0 - WIN + 1) >> 6;
  if (ktlo < 0) ktlo = 0;
  const int kthi = q0 >> 6;

  for (int kt = ktlo; kt <= kthi; ++kt) {
    __syncthreads();
#pragma unroll
    for (int p = 0; p < 4; ++p) {  // K stage, f32->bf16, XOR swizzle
      int idx = p * 256 + t;
      int row = idx >> 4, cs = idx & 15;
      int c = cs ^ (row & 7);
      const float* sp = &Kbase[(size_t)(kt * 64 + row) * HD + c * 8];
      float4 f0 = *(const float4*)sp;
      float4 f1 = *(const float4*)(sp + 4);
      union { ushort u[8]; uint4 v; } pk;
      pk.u[0] = f2bf(f0.x); pk.u[1] = f2bf(f0.y);
      pk.u[2] = f2bf(f0.z); pk.u[3] = f2bf(f0.w);
      pk.u[4] = f2bf(f1.x); pk.u[5] = f2bf(f1.y);
      pk.u[6] = f2bf(f1.z); pk.u[7] = f2bf(f1.w);
      *(uint4*)&Kl[row * 128 + cs * 8] = pk.v;
    }
#pragma unroll
    for (int p = 0; p < 4; ++p) {  // V stage transposed [d][key]
      int idx = p * 256 + t;
      int key = idx & 63, dc = idx >> 6;
      const float* sp = &Vbase[(size_t)(kt * 64 + key) * HD + dc * 8];
      float4 f0 = *(const float4*)sp;
      float4 f1 = *(const float4*)(sp + 4);
      Vl[(dc * 8 + 0) * 72 + key] = f2bf(f0.x);
      Vl[(dc * 8 + 1) * 72 + key] = f2bf(f0.y);
      Vl[(dc * 8 + 2) * 72 + key] = f2bf(f0.z);
      Vl[(dc * 8 + 3) * 72 + key] = f2bf(f0.w);
      Vl[(dc * 8 + 4) * 72 + key] = f2bf(f1.x);
      Vl[(dc * 8 + 5) * 72 + key] = f2bf(f1.y);
      Vl[(dc * 8 + 6) * 72 + key] = f2bf(f1.z);
      Vl[(dc * 8 + 7) * 72 + key] = f2bf(f1.w);
    }
    __syncthreads();

    f32x4 sacc[4] = {};
#pragma unroll
    for (int ds = 0; ds < 4; ++ds) {
#pragma unroll
      for (int kf = 0; kf < 4; ++kf) {
        int key = kf * 16 + l15;
        bf16x8 kb = *(const bf16x8*)&Kl[key * 128 + (((ds * 4 + lg) ^ (key & 7)) * 8)];
        sacc[kf] = __builtin_amdgcn_mfma_f32_16x16x32_bf16(aq[ds], kb, sacc[kf], 0, 0, 0);
      }
    }

    const float scale = 0.08838834764831845f;  // 1/sqrt(128)
    const float L2E = 1.4426950408889634f;
#pragma unroll
    for (int r = 0; r < 4; ++r) {
      int q = q0 + w * 16 + lg * 4 + r;
      float sv[4];
      float mx = -1e30f;
#pragma unroll
      for (int kf = 0; kf < 4; ++kf) {
        int key = kt * 64 + kf * 16 + l15;
        float s = sacc[kf][r] * scale;
        bool valid = (key <= q) && (key + WIN > q);
        s = valid ? s : -1e30f;
        sv[kf] = s;
        mx = fmaxf(mx, s);
      }
      mx = fmaxf(mx, __shfl_xor(mx, 1));
      mx = fmaxf(mx, __shfl_xor(mx, 2));
      mx = fmaxf(mx, __shfl_xor(mx, 4));
      mx = fmaxf(mx, __shfl_xor(mx, 8));
      float mnew = fmaxf(mrow[r], mx);
      float sf = exp2f((mrow[r] - mnew) * L2E);
      float ps = 0.f;
#pragma unroll
      for (int kf = 0; kf < 4; ++kf) {
        float p = (sv[kf] > -1e29f) ? exp2f((sv[kf] - mnew) * L2E) : 0.f;
        ps += p;
        Pl[w * 1152 + (lg * 4 + r) * 72 + kf * 16 + l15] = f2bf(p);
      }
      ps += __shfl_xor(ps, 1);
      ps += __shfl_xor(ps, 2);
      ps += __shfl_xor(ps, 4);
      ps += __shfl_xor(ps, 8);
      lrow[r] = lrow[r] * sf + ps;
      mrow[r] = mnew;
#pragma unroll
      for (int nf = 0; nf < 8; ++nf) accc[nf][r] *= sf;
    }

#pragma unroll
    for (int ks = 0; ks < 2; ++ks) {  // PV
      bf16x8 pa = *(const bf16x8*)&Pl[w * 1152 + l15 * 72 + ks * 32 + lg * 8];
#pragma unroll
      for (int nf = 0; nf < 8; ++nf) {
        bf16x8 vb = *(const bf16x8*)&Vl[(nf * 16 + l15) * 72 + ks * 32 + lg * 8];
        accc[nf] = __builtin_amdgcn_mfma_f32_16x16x32_bf16(pa, vb, accc[nf], 0, 0, 0);
      }
    }
  }

#pragma unroll
  for (int r = 0; r < 4; ++r) {
    int q = q0 + w * 16 + lg * 4 + r;
    float inv = 1.0f / lrow[r];
    size_t rowoff = ((size_t)b * SEQ + q) * EMB + (size_t)h * HD;
#pragma unroll
    for (int nf = 0; nf < 8; ++nf)
      ctx[rowoff + nf * 16 + l15] = f2bf(accc[nf][r] * inv);
  }
}

// ---------------------------------------------------------------------------
extern "C" void kernel_launch(void* const* d_in, const int* in_sizes, int n_in,
                              void* d_out, int out_size, void* d_ws, size_t ws_size,
                              hipStream_t stream) {
  const float* x  = (const float*)d_in[0];
  const float* Wq = (const float*)d_in[1];
  const float* bq = (const float*)d_in[2];
  const float* Wk = (const float*)d_in[3];
  const float* bk = (const float*)d_in[4];
  const float* Wv = (const float*)d_in[5];
  const float* bv = (const float*)d_in[6];
  const float* Wo = (const float*)d_in[7];
  const float* bo = (const float*)d_in[8];
  float* out = (float*)d_out;
  ushort* ws = (ushort*)d_ws;
  // ws layout (ushort elems): Wt 4x4194304 | Qb 8388608 | xb/ctx 8388608 (aliased:
  // xb last read by gemm<1>; ctx first written by attn afterwards) = 67MB
  ushort* Wt   = ws;
  ushort* Qb   = ws + 16777216;
  ushort* xb   = ws + 25165824;
  ushort* ctxb = xb;

  xconv_kernel<<<4096, 256, 0, stream>>>(x, xb);
  wtrans_kernel<<<dim3(16, 64, 4), 256, 0, stream>>>(Wq, Wk, Wv, Wo, Wt);
  gemm_kernel<1><<<dim3(32, 16, 3), 256, 0, stream>>>(xb, Wt, bq, bk, bv, out, Qb);
  attn_kernel<<<dim3(32, 32), 256, 0, stream>>>(Qb, out + 8388608, out + 16777216, ctxb);
  gemm_kernel<0><<<dim3(32, 16, 1), 256, 0, stream>>>(ctxb, Wt + (size_t)3 * 4194304,
                                                      bo, nullptr, nullptr, out, nullptr);
}